// Round 7
// baseline (451.386 us; speedup 1.0000x reference)
//
#include <hip/hip_runtime.h>

// LambdaLayer2D: B=16, C=256, H=W=64, K=16, HEADS=4, U=1, V=64, R=7
#define B_ 16
#define C_ 256
#define N_ 4096            // H*W
#define NT_ 65536          // B*N
#define MH_ 240            // per-head-pair rows: 98 s + 2 ssum + 12 pad + 128 y_c

typedef _Float16 f16x8 __attribute__((ext_vector_type(8)));
typedef _Float16 f16x4 __attribute__((ext_vector_type(4)));
typedef _Float16 f16x2 __attribute__((ext_vector_type(2)));
typedef float    f32x4 __attribute__((ext_vector_type(4)));

__device__ __forceinline__ float waveSum(float v){
  #pragma unroll
  for (int off = 32; off > 0; off >>= 1) v += __shfl_xor(v, off, 64);
  return v;
}

// ---------------- K0: pack Wq|Wk|Wv -> fp16 [144][256]; wsumq --------
__global__ void k_pack_w(const float* __restrict__ Wq, const float* __restrict__ Wk,
                         const float* __restrict__ Wv, const float* __restrict__ pos_w,
                         _Float16* __restrict__ Wcat, float* __restrict__ wsumq){
  int idx = blockIdx.x * 256 + threadIdx.x;   // 144*256 = 36864
  int row = idx >> 8, col = idx & 255;
  float v;
  if (row < 64)      v = Wq[row * 256 + col];
  else if (row < 80) v = Wk[(row - 64) * 256 + col];
  else               v = Wv[(row - 80) * 256 + col];
  Wcat[idx] = (_Float16)v;
  if (idx < 16){
    float s = 0.f;
    for (int t = 0; t < 49; ++t) s += pos_w[idx * 49 + t];
    wsumq[idx] = s;
  }
}

// ---------------- K1: projection GEMM + BN partials + exp(k) ---------
// Emits: q16/v16 pixel-major f16, ek16[n][16] = exp(k) f16, per-block BN
// partial sums for the 128 BN'd channels, per-block sum-exp partials.
__global__ __launch_bounds__(256) void k_proj(const float* __restrict__ x,
                                              const _Float16* __restrict__ Wcat,
                                              _Float16* __restrict__ q16,
                                              _Float16* __restrict__ v16,
                                              _Float16* __restrict__ ek16,
                                              float* __restrict__ bnpart,
                                              float* __restrict__ kpart){
  __shared__ float bsumW[4][128];
  __shared__ float bssqW[4][128];
  __shared__ float ksumW[4][16];

  const int lane = threadIdx.x & 63;
  const int wid  = threadIdx.x >> 6;
  const int tile = blockIdx.x * 4 + wid;   // 0..4095
  const int j0 = tile << 4;
  const int b  = j0 >> 12;
  const int n0 = j0 & 4095;
  const int cl = lane & 15;
  const int kg = lane >> 4;

  f32x4 acc[9];
  #pragma unroll
  for (int m = 0; m < 9; ++m){ acc[m][0]=0.f; acc[m][1]=0.f; acc[m][2]=0.f; acc[m][3]=0.f; }

  const float* xb = x + (size_t)b * C_ * N_ + n0 + cl;
  #pragma unroll
  for (int kk = 0; kk < 8; ++kk){
    const int kb = kk * 32 + kg * 8;
    f16x8 bfrag;
    #pragma unroll
    for (int jj = 0; jj < 8; ++jj) bfrag[jj] = (_Float16)xb[(size_t)(kb + jj) * N_];
    #pragma unroll
    for (int m = 0; m < 9; ++m){
      f16x8 afrag = *reinterpret_cast<const f16x8*>(Wcat + ((m * 16 + cl) << 8) + kb);
      acc[m] = __builtin_amdgcn_mfma_f32_16x16x32_f16(afrag, bfrag, acc[m], 0, 0, 0);
    }
  }

  // exp(k) rows (Wcat rows 64..79): pixel-major f16 + wave partial sums
  {
    float eks[4];
    f16x4 h4;
    #pragma unroll
    for (int r = 0; r < 4; ++r){ eks[r] = __expf(acc[4][r]); h4[r] = (_Float16)eks[r]; }
    *reinterpret_cast<f16x4*>(ek16 + (((size_t)(j0 + cl)) << 4) + kg * 4) = h4;
    #pragma unroll
    for (int r = 0; r < 4; ++r){
      #pragma unroll
      for (int off = 1; off < 16; off <<= 1) eks[r] += __shfl_xor(eks[r], off, 64);
      if (cl == 0) ksumW[wid][kg * 4 + r] = eks[r];
    }
  }

  // pixel-major f16 q/v
  const size_t prow = ((size_t)(j0 + cl)) << 6;
  #pragma unroll
  for (int m = 0; m < 4; ++m){
    f16x4 h4;
    #pragma unroll
    for (int r = 0; r < 4; ++r) h4[r] = (_Float16)acc[m][r];
    *reinterpret_cast<f16x4*>(q16 + prow + m * 16 + kg * 4) = h4;
  }
  #pragma unroll
  for (int m = 5; m < 9; ++m){
    f16x4 h4;
    #pragma unroll
    for (int r = 0; r < 4; ++r) h4[r] = (_Float16)acc[m][r];
    *reinterpret_cast<f16x4*>(v16 + prow + (m - 5) * 16 + kg * 4) = h4;
  }

  // BN partials: reduce each row over this wave's 16 pixels
  #pragma unroll
  for (int m = 0; m < 9; ++m){
    if (m == 4) continue;
    #pragma unroll
    for (int r = 0; r < 4; ++r){
      float sv = acc[m][r];
      float sq = sv * sv;
      #pragma unroll
      for (int off = 1; off < 16; off <<= 1){
        sv += __shfl_xor(sv, off, 64);
        sq += __shfl_xor(sq, off, 64);
      }
      if (cl == 0){
        int idx = ((m < 4) ? m * 16 : (m - 5) * 16 + 64) + kg * 4 + r;
        bsumW[wid][idx] = sv;
        bssqW[wid][idx] = sq;
      }
    }
  }
  __syncthreads();
  if (threadIdx.x < 128){
    int i = threadIdx.x;
    float s  = bsumW[0][i] + bsumW[1][i] + bsumW[2][i] + bsumW[3][i];
    float sq = bssqW[0][i] + bssqW[1][i] + bssqW[2][i] + bssqW[3][i];
    bnpart[(size_t)i * 1024 + blockIdx.x]         = s;
    bnpart[(size_t)(i + 128) * 1024 + blockIdx.x] = sq;
  } else if (threadIdx.x < 144){
    int t = threadIdx.x - 128;    // kc 0..15
    float s = ksumW[0][t] + ksumW[1][t] + ksumW[2][t] + ksumW[3][t];
    kpart[(size_t)((blockIdx.x >> 6) * 16 + t) * 64 + (blockIdx.x & 63)] = s;
  }
}

// ---------------- K2: finalize BN affine + sum-exp --------------------
// blocks 0..127: BN channel; block 128: kstat[256] = 1/sumexp
// stats layout: [0:64) aq, [64:128) cq, [128:192) av, [192:256) cv
__global__ void k_bn2(const float* __restrict__ bnpart, const float* __restrict__ kpart,
                      const float* __restrict__ gq, const float* __restrict__ bq,
                      const float* __restrict__ gv, const float* __restrict__ bv,
                      float* __restrict__ stats, float* __restrict__ kstat){
  if (blockIdx.x == 128){
    int t = threadIdx.x;          // 0..255 = b*16+kc
    float s = 0.f;
    #pragma unroll
    for (int i = 0; i < 64; ++i) s += kpart[(size_t)t * 64 + i];
    kstat[t] = 1.f / s;
    return;
  }
  const int ch = blockIdx.x;       // 0..127
  const int t = threadIdx.x;
  float s = 0.f, ss = 0.f;
  #pragma unroll
  for (int k = 0; k < 4; ++k){
    int bk = t + k * 256;
    s  += bnpart[(size_t)ch * 1024 + bk];
    ss += bnpart[(size_t)(ch + 128) * 1024 + bk];
  }
  __shared__ float r0[4], r1[4];
  const int lane = t & 63, wid = t >> 6;
  s = waveSum(s); ss = waveSum(ss);
  if (lane == 0){ r0[wid] = s; r1[wid] = ss; }
  __syncthreads();
  if (t == 0){
    s  = r0[0] + r0[1] + r0[2] + r0[3];
    ss = r1[0] + r1[1] + r1[2] + r1[3];
    float mean = s * (1.f / NT_);
    float var  = ss * (1.f / NT_) - mean * mean;   // biased
    float rs = rsqrtf(var + 1e-5f);
    if (ch < 64){
      float a = rs * gq[ch];
      stats[ch] = a; stats[64 + ch] = bq[ch] - mean * a;
    } else {
      int v = ch - 64;
      float a = rs * gv[v];
      stats[128 + v] = a; stats[192 + v] = bv[v] - mean * a;
    }
  }
}

// ---------------- K3: lambda_c partials: 16 kc x 64 v per 64-px slice -
__global__ __launch_bounds__(256) void k_lam1(const _Float16* __restrict__ ek16,
                          const _Float16* __restrict__ v16,
                          const float* __restrict__ kstat,
                          float* __restrict__ lc_part){
  const int blk = blockIdx.x;                 // b*64 + sl
  const int b = blk >> 6, sl = blk & 63;
  const int tid = threadIdx.x;
  const int kc = tid >> 4, vg = tid & 15;
  __shared__ float skb[16][65];

  const size_t base = (size_t)b * N_ + sl * 64;
  if (tid < 128){
    int px = tid >> 1, part = tid & 1;
    f16x8 e8 = *reinterpret_cast<const f16x8*>(ek16 + ((base + px) << 4) + part * 8);
    #pragma unroll
    for (int j = 0; j < 8; ++j)
      skb[part * 8 + j][px] = (float)e8[j] * kstat[b * 16 + part * 8 + j];
  }
  __syncthreads();

  float S0 = 0.f, S1 = 0.f, S2 = 0.f, S3 = 0.f;
  const _Float16* vbase = v16 + (base << 6) + vg * 4;
  #pragma unroll 8
  for (int j = 0; j < 64; ++j){
    f16x4 v4 = *reinterpret_cast<const f16x4*>(vbase + ((size_t)j << 6));
    float sk = skb[kc][j];
    S0 += sk * (float)v4[0];
    S1 += sk * (float)v4[1];
    S2 += sk * (float)v4[2];
    S3 += sk * (float)v4[3];
  }
  float4 w; w.x = S0; w.y = S1; w.z = S2; w.w = S3;
  *reinterpret_cast<float4*>(lc_part + (size_t)blk * 1024 + kc * 64 + vg * 4) = w;
}

// ---------------- K4: build per-(batch, head-pair) weight [240][32] ---
// rows 0..97: s rows (h',tap); 98..99: ssum (h'); 100..111: zero;
// 112..239: y_c rows (h', permuted v). lambda_c finalize folded in.
__global__ void k_makeW(const float* __restrict__ stats, const float* __restrict__ lc_part,
                        const float* __restrict__ pos_w, const float* __restrict__ pos_b,
                        const float* __restrict__ wsumq,
                        _Float16* __restrict__ Wbig2, float* __restrict__ Bbig2){
  const int b = blockIdx.x >> 2, qr = blockIdx.x & 3;
  __shared__ float lcq[16][64];
  for (int o = threadIdx.x; o < 1024; o += 256){
    int kc = o >> 6, v = o & 63;
    float s = 0.f;
    for (int sl = 0; sl < 64; ++sl) s += lc_part[(size_t)(b * 64 + sl) * 1024 + o];
    lcq[kc][v] = stats[128 + v] * s + stats[192 + v] + pos_b[kc];
  }
  __syncthreads();

  const int idx = qr * 120 + threadIdx.x;     // 0..479
  if (threadIdx.x >= 120 || idx >= 480) return;
  const int half = idx / MH_, r = idx % MH_;
  const int rowg = (b * 2 + half) * MH_ + r;
  _Float16* wrow = Wbig2 + ((size_t)rowg << 5);
  float bias = 0.f;
  if (r < 100){
    const int h_ = (r < 98) ? (r / 49) : (r - 98);
    const int h = half * 2 + h_;
    if (r < 98){
      const int tap = r % 49;
      for (int c2 = 0; c2 < 32; ++c2){
        int qc = half * 32 + c2;
        wrow[c2] = (_Float16)(((c2 >> 4) == h_) ? stats[qc] * pos_w[(qc & 15) * 49 + tap] : 0.f);
      }
      for (int k = 0; k < 16; ++k) bias += stats[64 + h * 16 + k] * pos_w[k * 49 + tap];
    } else {
      for (int c2 = 0; c2 < 32; ++c2){
        int qc = half * 32 + c2;
        wrow[c2] = (_Float16)(((c2 >> 4) == h_) ? stats[qc] * wsumq[qc & 15] : 0.f);
      }
      for (int k = 0; k < 16; ++k) bias += stats[64 + h * 16 + k] * wsumq[k];
    }
  } else if (r < 112){
    for (int c2 = 0; c2 < 32; ++c2) wrow[c2] = (_Float16)0.f;
  } else {
    const int t = r - 112, h_ = t >> 6, vv = t & 63;
    const int h = half * 2 + h_;
    // position vv = vhi*16 + kg*4 + r2 holds v = kg*16 + vhi*4 + r2
    const int v = (((vv >> 2) & 3) << 4) | ((vv >> 4) << 2) | (vv & 3);
    for (int c2 = 0; c2 < 32; ++c2){
      int qc = half * 32 + c2;
      wrow[c2] = (_Float16)(((c2 >> 4) == h_) ? stats[qc] * lcq[qc & 15][v] : 0.f);
    }
    for (int k = 0; k < 16; ++k) bias += stats[64 + h * 16 + k] * lcq[k][v];
  }
  Bbig2[rowg] = bias;
}

// ---------------- K5: fused S-GEMM + y_c-GEMM + banded conv ----------
// Head-pair split: grid z = b*2 + half. 16x4 pixel tile, 4 waves. K=32
// MFMA (one k-step), acc[15] (60 regs) -> 4 waves/SIMD. LDS 32 KB:
// XOR-swizzled vn + per-dy parity s-buffer (per-wave, no barriers).
__global__ __launch_bounds__(256, 4) void k_fused(
                        const _Float16* __restrict__ q16,
                        const _Float16* __restrict__ v16,
                        const float* __restrict__ stats,
                        const _Float16* __restrict__ Wbig2,
                        const float* __restrict__ Bbig2,
                        float* __restrict__ out){
  __shared__ _Float16 vn_s[220 * 64];      // 28160 B, XOR-swizzled (16B gran)
  __shared__ _Float16 s_s[4][2][16][18];   // 4608 B, [wave][dy&1][pix][dx*2+h']

  const int zb = blockIdx.z;
  const int b = zb >> 1, ha = zb & 1;
  const int x0 = blockIdx.x * 16;
  const int y0 = blockIdx.y * 4;
  const int tid = threadIdx.x;
  const int lane = tid & 63, wid = tid >> 6;
  const int cl = lane & 15, kg = lane >> 4;
  const size_t bN = (size_t)b * N_;

  // ---- vn halo staging: 220 pos x 64 v, coalesced 16B loads ----
  for (int idx = tid; idx < 1760; idx += 256){
    int pos = idx >> 3, c8 = (idx & 7) << 3;
    int yy = pos / 22, xx = pos - yy * 22;
    int gy = y0 + yy - 3, gx = x0 + xx - 3;
    f16x8 val;
    #pragma unroll
    for (int j = 0; j < 8; ++j) val[j] = (_Float16)0.f;
    if ((unsigned)gy < 64u && (unsigned)gx < 64u)
      val = *reinterpret_cast<const f16x8*>(v16 + ((bN + gy * 64 + gx) << 6) + c8);
    int e = (pos << 6) + c8;
    *reinterpret_cast<f16x8*>(&vn_s[e ^ ((pos & 7) << 3)]) = val;
  }

  // ---- MFMA phase: 15 row-tiles, K=32 (this half's q channels) ----
  const int pix = (y0 + wid) * 64 + x0 + cl;
  const _Float16* qp = q16 + ((bN + pix) << 6) + ha * 32;
  f16x8 bfrag = *reinterpret_cast<const f16x8*>(qp + kg * 8);
  const _Float16* Wb = Wbig2 + (((size_t)(b * 2 + ha) * MH_) << 5);
  const float* Bb = Bbig2 + (b * 2 + ha) * MH_;

  f32x4 acc[15];
  #pragma unroll
  for (int m = 0; m < 15; ++m){ acc[m][0]=0.f; acc[m][1]=0.f; acc[m][2]=0.f; acc[m][3]=0.f; }

  #pragma unroll
  for (int m = 0; m < 15; ++m){
    f16x8 a0 = *reinterpret_cast<const f16x8*>(Wb + ((m * 16 + cl) << 5) + kg * 8);
    acc[m] = __builtin_amdgcn_mfma_f32_16x16x32_f16(a0, bfrag, acc[m], 0, 0, 0);
  }

  // ---- bias pre-add (row = m*16 + kg*4 + r for all 15 tiles) ----
  #pragma unroll
  for (int m = 0; m < 15; ++m)
    acc[m] += *reinterpret_cast<const f32x4*>(Bb + m * 16 + kg * 4);

  // ---- ssum rows 98,99 live in kg=0's acc[6][2],acc[6][3] ----
  const float ssum0 = __shfl(acc[6][2], cl, 64);
  const float ssum1 = __shfl(acc[6][3], cl, 64);
  __syncthreads();   // vn_s ready

  // ---- band: 49 taps; per-dy write of 14 S rows into parity buffer ----
  f16x2 accB[2][8];
  #pragma unroll
  for (int h_ = 0; h_ < 2; ++h_)
    #pragma unroll
    for (int j = 0; j < 8; ++j){ accB[h_][j][0] = (_Float16)0.f; accB[h_][j][1] = (_Float16)0.f; }

  #pragma unroll
  for (int dy = 0; dy < 7; ++dy){
    #pragma unroll
    for (int h_ = 0; h_ < 2; ++h_)
      #pragma unroll
      for (int dx = 0; dx < 7; ++dx){
        const int row = h_ * 49 + dy * 7 + dx;
        if (((row >> 2) & 3) == kg)
          s_s[wid][dy & 1][cl][dx * 2 + h_] = (_Float16)acc[row >> 4][row & 3];
      }
    const _Float16* srow = &s_s[wid][dy & 1][cl][0];
    #pragma unroll
    for (int dx = 0; dx < 7; ++dx){
      const int pos = (wid + dy) * 22 + (cl + dx);
      f16x2 s2 = *reinterpret_cast<const f16x2*>(srow + dx * 2);
      const int esw = ((pos << 6) + (kg << 4)) ^ ((pos & 7) << 3);
      f16x8 va = *reinterpret_cast<const f16x8*>(&vn_s[esw]);
      f16x8 vb = *reinterpret_cast<const f16x8*>(&vn_s[esw ^ 8]);
      f16x2 p0 = __builtin_shufflevector(va, va, 0, 1);
      f16x2 p1 = __builtin_shufflevector(va, va, 2, 3);
      f16x2 p2 = __builtin_shufflevector(va, va, 4, 5);
      f16x2 p3 = __builtin_shufflevector(va, va, 6, 7);
      f16x2 p4 = __builtin_shufflevector(vb, vb, 0, 1);
      f16x2 p5 = __builtin_shufflevector(vb, vb, 2, 3);
      f16x2 p6 = __builtin_shufflevector(vb, vb, 4, 5);
      f16x2 p7 = __builtin_shufflevector(vb, vb, 6, 7);
      #pragma unroll
      for (int h_ = 0; h_ < 2; ++h_){
        f16x2 sh; sh[0] = s2[h_]; sh[1] = s2[h_];
        accB[h_][0] = sh * p0 + accB[h_][0];
        accB[h_][1] = sh * p1 + accB[h_][1];
        accB[h_][2] = sh * p2 + accB[h_][2];
        accB[h_][3] = sh * p3 + accB[h_][3];
        accB[h_][4] = sh * p4 + accB[h_][4];
        accB[h_][5] = sh * p5 + accB[h_][5];
        accB[h_][6] = sh * p6 + accB[h_][6];
        accB[h_][7] = sh * p7 + accB[h_][7];
      }
    }
  }

  // ---- merge y_c (biased acc, permuted rows) + a_v*band + c_v*ssum ----
  float* ob = out + ((size_t)b * 256) * N_ + pix;
  f32x4 av[4], cv[4];
  #pragma unroll
  for (int vhi = 0; vhi < 4; ++vhi){
    av[vhi] = *reinterpret_cast<const f32x4*>(stats + 128 + kg * 16 + vhi * 4);
    cv[vhi] = *reinterpret_cast<const f32x4*>(stats + 192 + kg * 16 + vhi * 4);
  }
  #pragma unroll
  for (int h_ = 0; h_ < 2; ++h_){
    const float ss = h_ ? ssum1 : ssum0;
    #pragma unroll
    for (int vhi = 0; vhi < 4; ++vhi){
      const int m = 7 + h_ * 4 + vhi;
      #pragma unroll
      for (int r = 0; r < 4; ++r){
        const int j = vhi * 4 + r;                       // v offset in kg chunk
        const int ch = (ha * 2 + h_) * 64 + kg * 16 + j; // output channel
        const float band = (float)accB[h_][j >> 1][j & 1];
        ob[(size_t)ch * N_] = acc[m][r] + av[vhi][r] * band + cv[vhi][r] * ss;
      }
    }
  }
}

extern "C" void kernel_launch(void* const* d_in, const int* in_sizes, int n_in,
                              void* d_out, int out_size, void* d_ws, size_t ws_size,
                              hipStream_t stream){
  (void)in_sizes; (void)n_in; (void)out_size; (void)ws_size;
  const float* x  = (const float*)d_in[0];
  const float* Wq = (const float*)d_in[1];
  const float* Wk = (const float*)d_in[2];
  const float* Wv = (const float*)d_in[3];
  const float* gq = (const float*)d_in[4];
  const float* bq = (const float*)d_in[5];
  const float* gv = (const float*)d_in[6];
  const float* bv = (const float*)d_in[7];
  const float* pw = (const float*)d_in[8];
  const float* pb = (const float*)d_in[9];
  float* out = (float*)d_out;

  char* ws = (char*)d_ws;
  size_t off = 0;
  _Float16* Wcat  = (_Float16*)(ws + off);  off += 131072;                      // 73,728 used
  _Float16* q16   = (_Float16*)(ws + off);  off += (size_t)NT_ * 64 * 2;        // 8,388,608
  _Float16* v16   = (_Float16*)(ws + off);  off += (size_t)NT_ * 64 * 2;        // 8,388,608
  _Float16* ek16  = (_Float16*)(ws + off);  off += (size_t)NT_ * 16 * 2;        // 2,097,152
  _Float16* Wbig2 = (_Float16*)(ws + off);  off += (size_t)B_ * 2 * MH_ * 32 * 2; // 491,520
  float*    Bbig2 = (float*)(ws + off);     off += (size_t)B_ * 2 * MH_ * 4;    // 61,440
  float*    stats = (float*)(ws + off);     off += 1024;
  float*    kstat = (float*)(ws + off);     off += 1024;
  float*    wsumq = (float*)(ws + off);     off += 1024;
  float*    lc_part = (float*)(ws + off);   off += (size_t)1024 * 1024 * 4;     // 4,194,304
  float*    bnpart  = (float*)(ws + off);   off += (size_t)256 * 1024 * 4;      // 1,048,576
  float*    kpart   = (float*)(ws + off);   off += (size_t)256 * 64 * 4;        // 65,536

  k_pack_w <<<144, 256, 0, stream>>>(Wq, Wk, Wv, pw, Wcat, wsumq);
  k_proj   <<<1024, 256, 0, stream>>>(x, Wcat, q16, v16, ek16, bnpart, kpart);
  k_bn2    <<<129, 256, 0, stream>>>(bnpart, kpart, gq, bq, gv, bv, stats, kstat);
  k_lam1   <<<1024, 256, 0, stream>>>(ek16, v16, kstat, lc_part);
  k_makeW  <<<64, 256, 0, stream>>>(stats, lc_part, pw, pb, wsumq, Wbig2, Bbig2);
  dim3 g5(4, 16, 32);
  k_fused  <<<g5, 256, 0, stream>>>(q16, v16, stats, Wbig2, Bbig2, out);
}

// Round 8
// 387.568 us; speedup vs baseline: 1.1647x; 1.1647x over previous
//
#include <hip/hip_runtime.h>

// LambdaLayer2D: B=16, C=256, H=W=64, K=16, HEADS=4, U=1, V=64, R=7
#define B_ 16
#define C_ 256
#define N_ 4096            // H*W
#define NT_ 65536          // B*N
#define MH_ 240            // per-head-pair rows: 98 s + 2 ssum + 12 pad + 128 y_c

typedef _Float16 f16x8 __attribute__((ext_vector_type(8)));
typedef _Float16 f16x4 __attribute__((ext_vector_type(4)));
typedef _Float16 f16x2 __attribute__((ext_vector_type(2)));
typedef float    f32x4 __attribute__((ext_vector_type(4)));

__device__ __forceinline__ float waveSum(float v){
  #pragma unroll
  for (int off = 32; off > 0; off >>= 1) v += __shfl_xor(v, off, 64);
  return v;
}

// ---------------- K0: pack Wq|Wk|Wv -> fp16 [144][256]; wsumq --------
__global__ void k_pack_w(const float* __restrict__ Wq, const float* __restrict__ Wk,
                         const float* __restrict__ Wv, const float* __restrict__ pos_w,
                         _Float16* __restrict__ Wcat, float* __restrict__ wsumq){
  int idx = blockIdx.x * 256 + threadIdx.x;   // 144*256 = 36864
  int row = idx >> 8, col = idx & 255;
  float v;
  if (row < 64)      v = Wq[row * 256 + col];
  else if (row < 80) v = Wk[(row - 64) * 256 + col];
  else               v = Wv[(row - 80) * 256 + col];
  Wcat[idx] = (_Float16)v;
  if (idx < 16){
    float s = 0.f;
    for (int t = 0; t < 49; ++t) s += pos_w[idx * 49 + t];
    wsumq[idx] = s;
  }
}

// ---------------- K1: projection GEMM + BN partials + exp(k) ---------
// Emits: q16/v16 pixel-major f16, ek16[n][16] = exp(k) f16, per-block BN
// partial sums for the 128 BN'd channels, per-block sum-exp partials.
__global__ __launch_bounds__(256) void k_proj(const float* __restrict__ x,
                                              const _Float16* __restrict__ Wcat,
                                              _Float16* __restrict__ q16,
                                              _Float16* __restrict__ v16,
                                              _Float16* __restrict__ ek16,
                                              float* __restrict__ bnpart,
                                              float* __restrict__ kpart){
  __shared__ float bsumW[4][128];
  __shared__ float bssqW[4][128];
  __shared__ float ksumW[4][16];

  const int lane = threadIdx.x & 63;
  const int wid  = threadIdx.x >> 6;
  const int tile = blockIdx.x * 4 + wid;   // 0..4095
  const int j0 = tile << 4;
  const int b  = j0 >> 12;
  const int n0 = j0 & 4095;
  const int cl = lane & 15;
  const int kg = lane >> 4;

  f32x4 acc[9];
  #pragma unroll
  for (int m = 0; m < 9; ++m){ acc[m][0]=0.f; acc[m][1]=0.f; acc[m][2]=0.f; acc[m][3]=0.f; }

  const float* xb = x + (size_t)b * C_ * N_ + n0 + cl;
  #pragma unroll
  for (int kk = 0; kk < 8; ++kk){
    const int kb = kk * 32 + kg * 8;
    f16x8 bfrag;
    #pragma unroll
    for (int jj = 0; jj < 8; ++jj) bfrag[jj] = (_Float16)xb[(size_t)(kb + jj) * N_];
    #pragma unroll
    for (int m = 0; m < 9; ++m){
      f16x8 afrag = *reinterpret_cast<const f16x8*>(Wcat + ((m * 16 + cl) << 8) + kb);
      acc[m] = __builtin_amdgcn_mfma_f32_16x16x32_f16(afrag, bfrag, acc[m], 0, 0, 0);
    }
  }

  // exp(k) rows (Wcat rows 64..79): pixel-major f16 + wave partial sums
  {
    float eks[4];
    f16x4 h4;
    #pragma unroll
    for (int r = 0; r < 4; ++r){ eks[r] = __expf(acc[4][r]); h4[r] = (_Float16)eks[r]; }
    *reinterpret_cast<f16x4*>(ek16 + (((size_t)(j0 + cl)) << 4) + kg * 4) = h4;
    #pragma unroll
    for (int r = 0; r < 4; ++r){
      #pragma unroll
      for (int off = 1; off < 16; off <<= 1) eks[r] += __shfl_xor(eks[r], off, 64);
      if (cl == 0) ksumW[wid][kg * 4 + r] = eks[r];
    }
  }

  // pixel-major f16 q/v
  const size_t prow = ((size_t)(j0 + cl)) << 6;
  #pragma unroll
  for (int m = 0; m < 4; ++m){
    f16x4 h4;
    #pragma unroll
    for (int r = 0; r < 4; ++r) h4[r] = (_Float16)acc[m][r];
    *reinterpret_cast<f16x4*>(q16 + prow + m * 16 + kg * 4) = h4;
  }
  #pragma unroll
  for (int m = 5; m < 9; ++m){
    f16x4 h4;
    #pragma unroll
    for (int r = 0; r < 4; ++r) h4[r] = (_Float16)acc[m][r];
    *reinterpret_cast<f16x4*>(v16 + prow + (m - 5) * 16 + kg * 4) = h4;
  }

  // BN partials: reduce each row over this wave's 16 pixels
  #pragma unroll
  for (int m = 0; m < 9; ++m){
    if (m == 4) continue;
    #pragma unroll
    for (int r = 0; r < 4; ++r){
      float sv = acc[m][r];
      float sq = sv * sv;
      #pragma unroll
      for (int off = 1; off < 16; off <<= 1){
        sv += __shfl_xor(sv, off, 64);
        sq += __shfl_xor(sq, off, 64);
      }
      if (cl == 0){
        int idx = ((m < 4) ? m * 16 : (m - 5) * 16 + 64) + kg * 4 + r;
        bsumW[wid][idx] = sv;
        bssqW[wid][idx] = sq;
      }
    }
  }
  __syncthreads();
  if (threadIdx.x < 128){
    int i = threadIdx.x;
    float s  = bsumW[0][i] + bsumW[1][i] + bsumW[2][i] + bsumW[3][i];
    float sq = bssqW[0][i] + bssqW[1][i] + bssqW[2][i] + bssqW[3][i];
    bnpart[(size_t)i * 1024 + blockIdx.x]         = s;
    bnpart[(size_t)(i + 128) * 1024 + blockIdx.x] = sq;
  } else if (threadIdx.x < 144){
    int t = threadIdx.x - 128;    // kc 0..15
    float s = ksumW[0][t] + ksumW[1][t] + ksumW[2][t] + ksumW[3][t];
    kpart[(size_t)((blockIdx.x >> 6) * 16 + t) * 64 + (blockIdx.x & 63)] = s;
  }
}

// ---------------- K2: finalize BN affine + sum-exp --------------------
// blocks 0..127: BN channel; block 128: kstat[256] = 1/sumexp
// stats layout: [0:64) aq, [64:128) cq, [128:192) av, [192:256) cv
__global__ void k_bn2(const float* __restrict__ bnpart, const float* __restrict__ kpart,
                      const float* __restrict__ gq, const float* __restrict__ bq,
                      const float* __restrict__ gv, const float* __restrict__ bv,
                      float* __restrict__ stats, float* __restrict__ kstat){
  if (blockIdx.x == 128){
    int t = threadIdx.x;          // 0..255 = b*16+kc
    float s = 0.f;
    #pragma unroll
    for (int i = 0; i < 64; ++i) s += kpart[(size_t)t * 64 + i];
    kstat[t] = 1.f / s;
    return;
  }
  const int ch = blockIdx.x;       // 0..127
  const int t = threadIdx.x;
  float s = 0.f, ss = 0.f;
  #pragma unroll
  for (int k = 0; k < 4; ++k){
    int bk = t + k * 256;
    s  += bnpart[(size_t)ch * 1024 + bk];
    ss += bnpart[(size_t)(ch + 128) * 1024 + bk];
  }
  __shared__ float r0[4], r1[4];
  const int lane = t & 63, wid = t >> 6;
  s = waveSum(s); ss = waveSum(ss);
  if (lane == 0){ r0[wid] = s; r1[wid] = ss; }
  __syncthreads();
  if (t == 0){
    s  = r0[0] + r0[1] + r0[2] + r0[3];
    ss = r1[0] + r1[1] + r1[2] + r1[3];
    float mean = s * (1.f / NT_);
    float var  = ss * (1.f / NT_) - mean * mean;   // biased
    float rs = rsqrtf(var + 1e-5f);
    if (ch < 64){
      float a = rs * gq[ch];
      stats[ch] = a; stats[64 + ch] = bq[ch] - mean * a;
    } else {
      int v = ch - 64;
      float a = rs * gv[v];
      stats[128 + v] = a; stats[192 + v] = bv[v] - mean * a;
    }
  }
}

// ---------------- K3: lambda_c partials: 16 kc x 64 v per 64-px slice -
__global__ __launch_bounds__(256) void k_lam1(const _Float16* __restrict__ ek16,
                          const _Float16* __restrict__ v16,
                          const float* __restrict__ kstat,
                          float* __restrict__ lc_part){
  const int blk = blockIdx.x;                 // b*64 + sl
  const int b = blk >> 6, sl = blk & 63;
  const int tid = threadIdx.x;
  const int kc = tid >> 4, vg = tid & 15;
  __shared__ float skb[16][65];

  const size_t base = (size_t)b * N_ + sl * 64;
  if (tid < 128){
    int px = tid >> 1, part = tid & 1;
    f16x8 e8 = *reinterpret_cast<const f16x8*>(ek16 + ((base + px) << 4) + part * 8);
    #pragma unroll
    for (int j = 0; j < 8; ++j)
      skb[part * 8 + j][px] = (float)e8[j] * kstat[b * 16 + part * 8 + j];
  }
  __syncthreads();

  float S0 = 0.f, S1 = 0.f, S2 = 0.f, S3 = 0.f;
  const _Float16* vbase = v16 + (base << 6) + vg * 4;
  #pragma unroll 8
  for (int j = 0; j < 64; ++j){
    f16x4 v4 = *reinterpret_cast<const f16x4*>(vbase + ((size_t)j << 6));
    float sk = skb[kc][j];
    S0 += sk * (float)v4[0];
    S1 += sk * (float)v4[1];
    S2 += sk * (float)v4[2];
    S3 += sk * (float)v4[3];
  }
  float4 w; w.x = S0; w.y = S1; w.z = S2; w.w = S3;
  *reinterpret_cast<float4*>(lc_part + (size_t)blk * 1024 + kc * 64 + vg * 4) = w;
}

// ---------------- K4: build per-(batch, head-pair) weight [240][32] ---
// rows 0..97: s rows (h',tap); 98..99: ssum (h'); 100..111: zero;
// 112..239: y_c rows (h', permuted v). lambda_c finalize folded in.
__global__ void k_makeW(const float* __restrict__ stats, const float* __restrict__ lc_part,
                        const float* __restrict__ pos_w, const float* __restrict__ pos_b,
                        const float* __restrict__ wsumq,
                        _Float16* __restrict__ Wbig2, float* __restrict__ Bbig2){
  const int b = blockIdx.x >> 2, qr = blockIdx.x & 3;
  __shared__ float lcq[16][64];
  for (int o = threadIdx.x; o < 1024; o += 256){
    int kc = o >> 6, v = o & 63;
    float s = 0.f;
    for (int sl = 0; sl < 64; ++sl) s += lc_part[(size_t)(b * 64 + sl) * 1024 + o];
    lcq[kc][v] = stats[128 + v] * s + stats[192 + v] + pos_b[kc];
  }
  __syncthreads();

  const int idx = qr * 120 + threadIdx.x;     // 0..479
  if (threadIdx.x >= 120 || idx >= 480) return;
  const int half = idx / MH_, r = idx % MH_;
  const int rowg = (b * 2 + half) * MH_ + r;
  _Float16* wrow = Wbig2 + ((size_t)rowg << 5);
  float bias = 0.f;
  if (r < 100){
    const int h_ = (r < 98) ? (r / 49) : (r - 98);
    const int h = half * 2 + h_;
    if (r < 98){
      const int tap = r % 49;
      for (int c2 = 0; c2 < 32; ++c2){
        int qc = half * 32 + c2;
        wrow[c2] = (_Float16)(((c2 >> 4) == h_) ? stats[qc] * pos_w[(qc & 15) * 49 + tap] : 0.f);
      }
      for (int k = 0; k < 16; ++k) bias += stats[64 + h * 16 + k] * pos_w[k * 49 + tap];
    } else {
      for (int c2 = 0; c2 < 32; ++c2){
        int qc = half * 32 + c2;
        wrow[c2] = (_Float16)(((c2 >> 4) == h_) ? stats[qc] * wsumq[qc & 15] : 0.f);
      }
      for (int k = 0; k < 16; ++k) bias += stats[64 + h * 16 + k] * wsumq[k];
    }
  } else if (r < 112){
    for (int c2 = 0; c2 < 32; ++c2) wrow[c2] = (_Float16)0.f;
  } else {
    const int t = r - 112, h_ = t >> 6, vv = t & 63;
    const int h = half * 2 + h_;
    // position vv = vhi*16 + kg*4 + r2 holds v = kg*16 + vhi*4 + r2
    const int v = (((vv >> 2) & 3) << 4) | ((vv >> 4) << 2) | (vv & 3);
    for (int c2 = 0; c2 < 32; ++c2){
      int qc = half * 32 + c2;
      wrow[c2] = (_Float16)(((c2 >> 4) == h_) ? stats[qc] * lcq[qc & 15][v] : 0.f);
    }
    for (int k = 0; k < 16; ++k) bias += stats[64 + h * 16 + k] * lcq[k][v];
  }
  Bbig2[rowg] = bias;
}

// ---------------- K5: fused S-GEMM + y_c-GEMM + banded conv ----------
// Head-pair split: grid z = b*2 + half. 16x4 pixel tile, 4 waves. K=32
// MFMA (one k-step), acc[15] (60 regs). launch_bounds(256,3): ~170-reg
// cap, NO SPILL (R7's (256,4) cap of 128 spilled the band loop -> 768MB
// scratch writes). LDS 32 KB; occupancy register-bound at 3 blk/CU.
__global__ __launch_bounds__(256, 3) void k_fused(
                        const _Float16* __restrict__ q16,
                        const _Float16* __restrict__ v16,
                        const float* __restrict__ stats,
                        const _Float16* __restrict__ Wbig2,
                        const float* __restrict__ Bbig2,
                        float* __restrict__ out){
  __shared__ _Float16 vn_s[220 * 64];      // 28160 B, XOR-swizzled (16B gran)
  __shared__ _Float16 s_s[4][2][16][18];   // 4608 B, [wave][dy&1][pix][dx*2+h']

  const int zb = blockIdx.z;
  const int b = zb >> 1, ha = zb & 1;
  const int x0 = blockIdx.x * 16;
  const int y0 = blockIdx.y * 4;
  const int tid = threadIdx.x;
  const int lane = tid & 63, wid = tid >> 6;
  const int cl = lane & 15, kg = lane >> 4;
  const size_t bN = (size_t)b * N_;

  // ---- vn halo staging: 220 pos x 64 v, coalesced 16B loads ----
  for (int idx = tid; idx < 1760; idx += 256){
    int pos = idx >> 3, c8 = (idx & 7) << 3;
    int yy = pos / 22, xx = pos - yy * 22;
    int gy = y0 + yy - 3, gx = x0 + xx - 3;
    f16x8 val;
    #pragma unroll
    for (int j = 0; j < 8; ++j) val[j] = (_Float16)0.f;
    if ((unsigned)gy < 64u && (unsigned)gx < 64u)
      val = *reinterpret_cast<const f16x8*>(v16 + ((bN + gy * 64 + gx) << 6) + c8);
    int e = (pos << 6) + c8;
    *reinterpret_cast<f16x8*>(&vn_s[e ^ ((pos & 7) << 3)]) = val;
  }

  // ---- MFMA phase: 15 row-tiles, K=32 (this half's q channels) ----
  const int pix = (y0 + wid) * 64 + x0 + cl;
  const _Float16* qp = q16 + ((bN + pix) << 6) + ha * 32;
  f16x8 bfrag = *reinterpret_cast<const f16x8*>(qp + kg * 8);
  const _Float16* Wb = Wbig2 + (((size_t)(b * 2 + ha) * MH_) << 5);
  const float* Bb = Bbig2 + (b * 2 + ha) * MH_;

  f32x4 acc[15];
  #pragma unroll
  for (int m = 0; m < 15; ++m){ acc[m][0]=0.f; acc[m][1]=0.f; acc[m][2]=0.f; acc[m][3]=0.f; }

  #pragma unroll
  for (int m = 0; m < 15; ++m){
    f16x8 a0 = *reinterpret_cast<const f16x8*>(Wb + ((m * 16 + cl) << 5) + kg * 8);
    acc[m] = __builtin_amdgcn_mfma_f32_16x16x32_f16(a0, bfrag, acc[m], 0, 0, 0);
  }

  // ---- bias pre-add (row = m*16 + kg*4 + r for all 15 tiles) ----
  #pragma unroll
  for (int m = 0; m < 15; ++m)
    acc[m] += *reinterpret_cast<const f32x4*>(Bb + m * 16 + kg * 4);

  // ---- ssum rows 98,99 live in kg=0's acc[6][2],acc[6][3] ----
  const float ssum0 = __shfl(acc[6][2], cl, 64);
  const float ssum1 = __shfl(acc[6][3], cl, 64);
  __syncthreads();   // vn_s ready

  // ---- band: 49 taps; per-dy write of 14 S rows into parity buffer ----
  f16x2 accB[2][8];
  #pragma unroll
  for (int h_ = 0; h_ < 2; ++h_)
    #pragma unroll
    for (int j = 0; j < 8; ++j){ accB[h_][j][0] = (_Float16)0.f; accB[h_][j][1] = (_Float16)0.f; }

  #pragma unroll
  for (int dy = 0; dy < 7; ++dy){
    #pragma unroll
    for (int h_ = 0; h_ < 2; ++h_)
      #pragma unroll
      for (int dx = 0; dx < 7; ++dx){
        const int row = h_ * 49 + dy * 7 + dx;
        if (((row >> 2) & 3) == kg)
          s_s[wid][dy & 1][cl][dx * 2 + h_] = (_Float16)acc[row >> 4][row & 3];
      }
    const _Float16* srow = &s_s[wid][dy & 1][cl][0];
    #pragma unroll
    for (int dx = 0; dx < 7; ++dx){
      const int pos = (wid + dy) * 22 + (cl + dx);
      f16x2 s2 = *reinterpret_cast<const f16x2*>(srow + dx * 2);
      const int esw = ((pos << 6) + (kg << 4)) ^ ((pos & 7) << 3);
      f16x8 va = *reinterpret_cast<const f16x8*>(&vn_s[esw]);
      f16x8 vb = *reinterpret_cast<const f16x8*>(&vn_s[esw ^ 8]);
      f16x2 p0 = __builtin_shufflevector(va, va, 0, 1);
      f16x2 p1 = __builtin_shufflevector(va, va, 2, 3);
      f16x2 p2 = __builtin_shufflevector(va, va, 4, 5);
      f16x2 p3 = __builtin_shufflevector(va, va, 6, 7);
      f16x2 p4 = __builtin_shufflevector(vb, vb, 0, 1);
      f16x2 p5 = __builtin_shufflevector(vb, vb, 2, 3);
      f16x2 p6 = __builtin_shufflevector(vb, vb, 4, 5);
      f16x2 p7 = __builtin_shufflevector(vb, vb, 6, 7);
      #pragma unroll
      for (int h_ = 0; h_ < 2; ++h_){
        f16x2 sh; sh[0] = s2[h_]; sh[1] = s2[h_];
        accB[h_][0] = sh * p0 + accB[h_][0];
        accB[h_][1] = sh * p1 + accB[h_][1];
        accB[h_][2] = sh * p2 + accB[h_][2];
        accB[h_][3] = sh * p3 + accB[h_][3];
        accB[h_][4] = sh * p4 + accB[h_][4];
        accB[h_][5] = sh * p5 + accB[h_][5];
        accB[h_][6] = sh * p6 + accB[h_][6];
        accB[h_][7] = sh * p7 + accB[h_][7];
      }
    }
  }

  // ---- merge y_c (biased acc, permuted rows) + a_v*band + c_v*ssum ----
  float* ob = out + ((size_t)b * 256) * N_ + pix;
  f32x4 av[4], cv[4];
  #pragma unroll
  for (int vhi = 0; vhi < 4; ++vhi){
    av[vhi] = *reinterpret_cast<const f32x4*>(stats + 128 + kg * 16 + vhi * 4);
    cv[vhi] = *reinterpret_cast<const f32x4*>(stats + 192 + kg * 16 + vhi * 4);
  }
  #pragma unroll
  for (int h_ = 0; h_ < 2; ++h_){
    const float ss = h_ ? ssum1 : ssum0;
    #pragma unroll
    for (int vhi = 0; vhi < 4; ++vhi){
      const int m = 7 + h_ * 4 + vhi;
      #pragma unroll
      for (int r = 0; r < 4; ++r){
        const int j = vhi * 4 + r;                       // v offset in kg chunk
        const int ch = (ha * 2 + h_) * 64 + kg * 16 + j; // output channel
        const float band = (float)accB[h_][j >> 1][j & 1];
        ob[(size_t)ch * N_] = acc[m][r] + av[vhi][r] * band + cv[vhi][r] * ss;
      }
    }
  }
}

extern "C" void kernel_launch(void* const* d_in, const int* in_sizes, int n_in,
                              void* d_out, int out_size, void* d_ws, size_t ws_size,
                              hipStream_t stream){
  (void)in_sizes; (void)n_in; (void)out_size; (void)ws_size;
  const float* x  = (const float*)d_in[0];
  const float* Wq = (const float*)d_in[1];
  const float* Wk = (const float*)d_in[2];
  const float* Wv = (const float*)d_in[3];
  const float* gq = (const float*)d_in[4];
  const float* bq = (const float*)d_in[5];
  const float* gv = (const float*)d_in[6];
  const float* bv = (const float*)d_in[7];
  const float* pw = (const float*)d_in[8];
  const float* pb = (const float*)d_in[9];
  float* out = (float*)d_out;

  char* ws = (char*)d_ws;
  size_t off = 0;
  _Float16* Wcat  = (_Float16*)(ws + off);  off += 131072;                      // 73,728 used
  _Float16* q16   = (_Float16*)(ws + off);  off += (size_t)NT_ * 64 * 2;        // 8,388,608
  _Float16* v16   = (_Float16*)(ws + off);  off += (size_t)NT_ * 64 * 2;        // 8,388,608
  _Float16* ek16  = (_Float16*)(ws + off);  off += (size_t)NT_ * 16 * 2;        // 2,097,152
  _Float16* Wbig2 = (_Float16*)(ws + off);  off += (size_t)B_ * 2 * MH_ * 32 * 2; // 491,520
  float*    Bbig2 = (float*)(ws + off);     off += (size_t)B_ * 2 * MH_ * 4;    // 61,440
  float*    stats = (float*)(ws + off);     off += 1024;
  float*    kstat = (float*)(ws + off);     off += 1024;
  float*    wsumq = (float*)(ws + off);     off += 1024;
  float*    lc_part = (float*)(ws + off);   off += (size_t)1024 * 1024 * 4;     // 4,194,304
  float*    bnpart  = (float*)(ws + off);   off += (size_t)256 * 1024 * 4;      // 1,048,576
  float*    kpart   = (float*)(ws + off);   off += (size_t)256 * 64 * 4;        // 65,536

  k_pack_w <<<144, 256, 0, stream>>>(Wq, Wk, Wv, pw, Wcat, wsumq);
  k_proj   <<<1024, 256, 0, stream>>>(x, Wcat, q16, v16, ek16, bnpart, kpart);
  k_bn2    <<<129, 256, 0, stream>>>(bnpart, kpart, gq, bq, gv, bv, stats, kstat);
  k_lam1   <<<1024, 256, 0, stream>>>(ek16, v16, kstat, lc_part);
  k_makeW  <<<64, 256, 0, stream>>>(stats, lc_part, pw, pb, wsumq, Wbig2, Bbig2);
  dim3 g5(4, 16, 32);
  k_fused  <<<g5, 256, 0, stream>>>(q16, v16, stats, Wbig2, Bbig2, out);
}

// Round 9
// 167.388 us; speedup vs baseline: 2.6966x; 2.3154x over previous
//
#include <hip/hip_runtime.h>

// LambdaLayer2D: B=16, C=256, H=W=64, K=16, HEADS=4, U=1, V=64, R=7
#define B_ 16
#define C_ 256
#define N_ 4096            // H*W
#define NT_ 65536          // B*N
#define MH_ 240            // per-head-pair rows: 98 s + 2 ssum + 12 pad + 128 y_c

typedef _Float16 f16x8 __attribute__((ext_vector_type(8)));
typedef _Float16 f16x4 __attribute__((ext_vector_type(4)));
typedef _Float16 f16x2 __attribute__((ext_vector_type(2)));
typedef float    f32x4 __attribute__((ext_vector_type(4)));

__device__ __forceinline__ float waveSum(float v){
  #pragma unroll
  for (int off = 32; off > 0; off >>= 1) v += __shfl_xor(v, off, 64);
  return v;
}

// ---------------- K0: pack Wq|Wk|Wv -> fp16 [144][256]; wsumq --------
__global__ void k_pack_w(const float* __restrict__ Wq, const float* __restrict__ Wk,
                         const float* __restrict__ Wv, const float* __restrict__ pos_w,
                         _Float16* __restrict__ Wcat, float* __restrict__ wsumq){
  int idx = blockIdx.x * 256 + threadIdx.x;   // 144*256 = 36864
  int row = idx >> 8, col = idx & 255;
  float v;
  if (row < 64)      v = Wq[row * 256 + col];
  else if (row < 80) v = Wk[(row - 64) * 256 + col];
  else               v = Wv[(row - 80) * 256 + col];
  Wcat[idx] = (_Float16)v;
  if (idx < 16){
    float s = 0.f;
    for (int t = 0; t < 49; ++t) s += pos_w[idx * 49 + t];
    wsumq[idx] = s;
  }
}

// ---------------- K1: projection GEMM + BN partials + exp(k) ---------
// Emits: q16/v16 pixel-major f16, ek16[n][16] = exp(k) f16, per-block BN
// partial sums for the 128 BN'd channels, per-block sum-exp partials.
__global__ __launch_bounds__(256) void k_proj(const float* __restrict__ x,
                                              const _Float16* __restrict__ Wcat,
                                              _Float16* __restrict__ q16,
                                              _Float16* __restrict__ v16,
                                              _Float16* __restrict__ ek16,
                                              float* __restrict__ bnpart,
                                              float* __restrict__ kpart){
  __shared__ float bsumW[4][128];
  __shared__ float bssqW[4][128];
  __shared__ float ksumW[4][16];

  const int lane = threadIdx.x & 63;
  const int wid  = threadIdx.x >> 6;
  const int tile = blockIdx.x * 4 + wid;   // 0..4095
  const int j0 = tile << 4;
  const int b  = j0 >> 12;
  const int n0 = j0 & 4095;
  const int cl = lane & 15;
  const int kg = lane >> 4;

  f32x4 acc[9];
  #pragma unroll
  for (int m = 0; m < 9; ++m){ acc[m][0]=0.f; acc[m][1]=0.f; acc[m][2]=0.f; acc[m][3]=0.f; }

  const float* xb = x + (size_t)b * C_ * N_ + n0 + cl;
  #pragma unroll
  for (int kk = 0; kk < 8; ++kk){
    const int kb = kk * 32 + kg * 8;
    f16x8 bfrag;
    #pragma unroll
    for (int jj = 0; jj < 8; ++jj) bfrag[jj] = (_Float16)xb[(size_t)(kb + jj) * N_];
    #pragma unroll
    for (int m = 0; m < 9; ++m){
      f16x8 afrag = *reinterpret_cast<const f16x8*>(Wcat + ((m * 16 + cl) << 8) + kb);
      acc[m] = __builtin_amdgcn_mfma_f32_16x16x32_f16(afrag, bfrag, acc[m], 0, 0, 0);
    }
  }

  // exp(k) rows (Wcat rows 64..79): pixel-major f16 + wave partial sums
  {
    float eks[4];
    f16x4 h4;
    #pragma unroll
    for (int r = 0; r < 4; ++r){ eks[r] = __expf(acc[4][r]); h4[r] = (_Float16)eks[r]; }
    *reinterpret_cast<f16x4*>(ek16 + (((size_t)(j0 + cl)) << 4) + kg * 4) = h4;
    #pragma unroll
    for (int r = 0; r < 4; ++r){
      #pragma unroll
      for (int off = 1; off < 16; off <<= 1) eks[r] += __shfl_xor(eks[r], off, 64);
      if (cl == 0) ksumW[wid][kg * 4 + r] = eks[r];
    }
  }

  // pixel-major f16 q/v
  const size_t prow = ((size_t)(j0 + cl)) << 6;
  #pragma unroll
  for (int m = 0; m < 4; ++m){
    f16x4 h4;
    #pragma unroll
    for (int r = 0; r < 4; ++r) h4[r] = (_Float16)acc[m][r];
    *reinterpret_cast<f16x4*>(q16 + prow + m * 16 + kg * 4) = h4;
  }
  #pragma unroll
  for (int m = 5; m < 9; ++m){
    f16x4 h4;
    #pragma unroll
    for (int r = 0; r < 4; ++r) h4[r] = (_Float16)acc[m][r];
    *reinterpret_cast<f16x4*>(v16 + prow + (m - 5) * 16 + kg * 4) = h4;
  }

  // BN partials: reduce each row over this wave's 16 pixels
  #pragma unroll
  for (int m = 0; m < 9; ++m){
    if (m == 4) continue;
    #pragma unroll
    for (int r = 0; r < 4; ++r){
      float sv = acc[m][r];
      float sq = sv * sv;
      #pragma unroll
      for (int off = 1; off < 16; off <<= 1){
        sv += __shfl_xor(sv, off, 64);
        sq += __shfl_xor(sq, off, 64);
      }
      if (cl == 0){
        int idx = ((m < 4) ? m * 16 : (m - 5) * 16 + 64) + kg * 4 + r;
        bsumW[wid][idx] = sv;
        bssqW[wid][idx] = sq;
      }
    }
  }
  __syncthreads();
  if (threadIdx.x < 128){
    int i = threadIdx.x;
    float s  = bsumW[0][i] + bsumW[1][i] + bsumW[2][i] + bsumW[3][i];
    float sq = bssqW[0][i] + bssqW[1][i] + bssqW[2][i] + bssqW[3][i];
    bnpart[(size_t)i * 1024 + blockIdx.x]         = s;
    bnpart[(size_t)(i + 128) * 1024 + blockIdx.x] = sq;
  } else if (threadIdx.x < 144){
    int t = threadIdx.x - 128;    // kc 0..15
    float s = ksumW[0][t] + ksumW[1][t] + ksumW[2][t] + ksumW[3][t];
    kpart[(size_t)((blockIdx.x >> 6) * 16 + t) * 64 + (blockIdx.x & 63)] = s;
  }
}

// ---------------- K2: finalize BN affine + sum-exp --------------------
// blocks 0..127: BN channel; block 128: kstat[256] = 1/sumexp
// stats layout: [0:64) aq, [64:128) cq, [128:192) av, [192:256) cv
__global__ void k_bn2(const float* __restrict__ bnpart, const float* __restrict__ kpart,
                      const float* __restrict__ gq, const float* __restrict__ bq,
                      const float* __restrict__ gv, const float* __restrict__ bv,
                      float* __restrict__ stats, float* __restrict__ kstat){
  if (blockIdx.x == 128){
    int t = threadIdx.x;          // 0..255 = b*16+kc
    float s = 0.f;
    #pragma unroll
    for (int i = 0; i < 64; ++i) s += kpart[(size_t)t * 64 + i];
    kstat[t] = 1.f / s;
    return;
  }
  const int ch = blockIdx.x;       // 0..127
  const int t = threadIdx.x;
  float s = 0.f, ss = 0.f;
  #pragma unroll
  for (int k = 0; k < 4; ++k){
    int bk = t + k * 256;
    s  += bnpart[(size_t)ch * 1024 + bk];
    ss += bnpart[(size_t)(ch + 128) * 1024 + bk];
  }
  __shared__ float r0[4], r1[4];
  const int lane = t & 63, wid = t >> 6;
  s = waveSum(s); ss = waveSum(ss);
  if (lane == 0){ r0[wid] = s; r1[wid] = ss; }
  __syncthreads();
  if (t == 0){
    s  = r0[0] + r0[1] + r0[2] + r0[3];
    ss = r1[0] + r1[1] + r1[2] + r1[3];
    float mean = s * (1.f / NT_);
    float var  = ss * (1.f / NT_) - mean * mean;   // biased
    float rs = rsqrtf(var + 1e-5f);
    if (ch < 64){
      float a = rs * gq[ch];
      stats[ch] = a; stats[64 + ch] = bq[ch] - mean * a;
    } else {
      int v = ch - 64;
      float a = rs * gv[v];
      stats[128 + v] = a; stats[192 + v] = bv[v] - mean * a;
    }
  }
}

// ---------------- K3: lambda_c partials: 16 kc x 64 v per 64-px slice -
__global__ __launch_bounds__(256) void k_lam1(const _Float16* __restrict__ ek16,
                          const _Float16* __restrict__ v16,
                          const float* __restrict__ kstat,
                          float* __restrict__ lc_part){
  const int blk = blockIdx.x;                 // b*64 + sl
  const int b = blk >> 6, sl = blk & 63;
  const int tid = threadIdx.x;
  const int kc = tid >> 4, vg = tid & 15;
  __shared__ float skb[16][65];

  const size_t base = (size_t)b * N_ + sl * 64;
  if (tid < 128){
    int px = tid >> 1, part = tid & 1;
    f16x8 e8 = *reinterpret_cast<const f16x8*>(ek16 + ((base + px) << 4) + part * 8);
    #pragma unroll
    for (int j = 0; j < 8; ++j)
      skb[part * 8 + j][px] = (float)e8[j] * kstat[b * 16 + part * 8 + j];
  }
  __syncthreads();

  float S0 = 0.f, S1 = 0.f, S2 = 0.f, S3 = 0.f;
  const _Float16* vbase = v16 + (base << 6) + vg * 4;
  #pragma unroll 8
  for (int j = 0; j < 64; ++j){
    f16x4 v4 = *reinterpret_cast<const f16x4*>(vbase + ((size_t)j << 6));
    float sk = skb[kc][j];
    S0 += sk * (float)v4[0];
    S1 += sk * (float)v4[1];
    S2 += sk * (float)v4[2];
    S3 += sk * (float)v4[3];
  }
  float4 w; w.x = S0; w.y = S1; w.z = S2; w.w = S3;
  *reinterpret_cast<float4*>(lc_part + (size_t)blk * 1024 + kc * 64 + vg * 4) = w;
}

// ---------------- K4: build per-(batch, head-pair) weight [240][32] ---
// rows 0..97: s rows (h',tap); 98..99: ssum (h'); 100..111: zero;
// 112..239: y_c rows (h', permuted v). lambda_c finalize folded in.
__global__ void k_makeW(const float* __restrict__ stats, const float* __restrict__ lc_part,
                        const float* __restrict__ pos_w, const float* __restrict__ pos_b,
                        const float* __restrict__ wsumq,
                        _Float16* __restrict__ Wbig2, float* __restrict__ Bbig2){
  const int b = blockIdx.x >> 2, qr = blockIdx.x & 3;
  __shared__ float lcq[16][64];
  for (int o = threadIdx.x; o < 1024; o += 256){
    int kc = o >> 6, v = o & 63;
    float s = 0.f;
    for (int sl = 0; sl < 64; ++sl) s += lc_part[(size_t)(b * 64 + sl) * 1024 + o];
    lcq[kc][v] = stats[128 + v] * s + stats[192 + v] + pos_b[kc];
  }
  __syncthreads();

  const int idx = qr * 120 + threadIdx.x;     // 0..479
  if (threadIdx.x >= 120 || idx >= 480) return;
  const int half = idx / MH_, r = idx % MH_;
  const int rowg = (b * 2 + half) * MH_ + r;
  _Float16* wrow = Wbig2 + ((size_t)rowg << 5);
  float bias = 0.f;
  if (r < 100){
    const int h_ = (r < 98) ? (r / 49) : (r - 98);
    const int h = half * 2 + h_;
    if (r < 98){
      const int tap = r % 49;
      for (int c2 = 0; c2 < 32; ++c2){
        int qc = half * 32 + c2;
        wrow[c2] = (_Float16)(((c2 >> 4) == h_) ? stats[qc] * pos_w[(qc & 15) * 49 + tap] : 0.f);
      }
      for (int k = 0; k < 16; ++k) bias += stats[64 + h * 16 + k] * pos_w[k * 49 + tap];
    } else {
      for (int c2 = 0; c2 < 32; ++c2){
        int qc = half * 32 + c2;
        wrow[c2] = (_Float16)(((c2 >> 4) == h_) ? stats[qc] * wsumq[qc & 15] : 0.f);
      }
      for (int k = 0; k < 16; ++k) bias += stats[64 + h * 16 + k] * wsumq[k];
    }
  } else if (r < 112){
    for (int c2 = 0; c2 < 32; ++c2) wrow[c2] = (_Float16)0.f;
  } else {
    const int t = r - 112, h_ = t >> 6, vv = t & 63;
    const int h = half * 2 + h_;
    // position vv = vhi*16 + kg*4 + r2 holds v = kg*16 + vhi*4 + r2
    const int v = (((vv >> 2) & 3) << 4) | ((vv >> 4) << 2) | (vv & 3);
    for (int c2 = 0; c2 < 32; ++c2){
      int qc = half * 32 + c2;
      wrow[c2] = (_Float16)(((c2 >> 4) == h_) ? stats[qc] * lcq[qc & 15][v] : 0.f);
    }
    for (int k = 0; k < 16; ++k) bias += stats[64 + h * 16 + k] * lcq[k][v];
  }
  Bbig2[rowg] = bias;
}

// ---------------- K5: fused S-GEMM + y_c-GEMM + banded conv ----------
// Head-pair split: grid z = b*2 + half. 16x4 pixel tile, 4 waves. K=32
// MFMA (one k-step), acc[15]. NO min-waves arg: empirically the arch-
// VGPR cap = 256/minWavesPerEU ((256,4)->64, (256,3)->84), which spilled
// the band loop (R7: 768MB, R8: 692MB scratch). Uncapped, demand ~150
// arch regs -> ~3 waves/SIMD on the unified file with zero spill.
__global__ __launch_bounds__(256) void k_fused(
                        const _Float16* __restrict__ q16,
                        const _Float16* __restrict__ v16,
                        const float* __restrict__ stats,
                        const _Float16* __restrict__ Wbig2,
                        const float* __restrict__ Bbig2,
                        float* __restrict__ out){
  __shared__ _Float16 vn_s[220 * 64];      // 28160 B, XOR-swizzled (16B gran)
  __shared__ _Float16 s_s[4][2][16][18];   // 4608 B, [wave][dy&1][pix][dx*2+h']

  const int zb = blockIdx.z;
  const int b = zb >> 1, ha = zb & 1;
  const int x0 = blockIdx.x * 16;
  const int y0 = blockIdx.y * 4;
  const int tid = threadIdx.x;
  const int lane = tid & 63, wid = tid >> 6;
  const int cl = lane & 15, kg = lane >> 4;
  const size_t bN = (size_t)b * N_;

  // ---- vn halo staging: 220 pos x 64 v, coalesced 16B loads ----
  for (int idx = tid; idx < 1760; idx += 256){
    int pos = idx >> 3, c8 = (idx & 7) << 3;
    int yy = pos / 22, xx = pos - yy * 22;
    int gy = y0 + yy - 3, gx = x0 + xx - 3;
    f16x8 val;
    #pragma unroll
    for (int j = 0; j < 8; ++j) val[j] = (_Float16)0.f;
    if ((unsigned)gy < 64u && (unsigned)gx < 64u)
      val = *reinterpret_cast<const f16x8*>(v16 + ((bN + gy * 64 + gx) << 6) + c8);
    int e = (pos << 6) + c8;
    *reinterpret_cast<f16x8*>(&vn_s[e ^ ((pos & 7) << 3)]) = val;
  }

  // ---- MFMA phase: 15 row-tiles, K=32 (this half's q channels) ----
  const int pix = (y0 + wid) * 64 + x0 + cl;
  const _Float16* qp = q16 + ((bN + pix) << 6) + ha * 32;
  f16x8 bfrag = *reinterpret_cast<const f16x8*>(qp + kg * 8);
  const _Float16* Wb = Wbig2 + (((size_t)(b * 2 + ha) * MH_) << 5);
  const float* Bb = Bbig2 + (b * 2 + ha) * MH_;

  f32x4 acc[15];
  #pragma unroll
  for (int m = 0; m < 15; ++m){ acc[m][0]=0.f; acc[m][1]=0.f; acc[m][2]=0.f; acc[m][3]=0.f; }

  #pragma unroll
  for (int m = 0; m < 15; ++m){
    f16x8 a0 = *reinterpret_cast<const f16x8*>(Wb + ((m * 16 + cl) << 5) + kg * 8);
    acc[m] = __builtin_amdgcn_mfma_f32_16x16x32_f16(a0, bfrag, acc[m], 0, 0, 0);
  }

  // ---- bias pre-add (row = m*16 + kg*4 + r for all 15 tiles) ----
  #pragma unroll
  for (int m = 0; m < 15; ++m)
    acc[m] += *reinterpret_cast<const f32x4*>(Bb + m * 16 + kg * 4);

  // ---- ssum rows 98,99 live in kg=0's acc[6][2],acc[6][3] ----
  const float ssum0 = __shfl(acc[6][2], cl, 64);
  const float ssum1 = __shfl(acc[6][3], cl, 64);
  __syncthreads();   // vn_s ready

  // ---- band: 49 taps; per-dy write of 14 S rows into parity buffer ----
  f16x2 accB[2][8];
  #pragma unroll
  for (int h_ = 0; h_ < 2; ++h_)
    #pragma unroll
    for (int j = 0; j < 8; ++j){ accB[h_][j][0] = (_Float16)0.f; accB[h_][j][1] = (_Float16)0.f; }

  #pragma unroll
  for (int dy = 0; dy < 7; ++dy){
    #pragma unroll
    for (int h_ = 0; h_ < 2; ++h_)
      #pragma unroll
      for (int dx = 0; dx < 7; ++dx){
        const int row = h_ * 49 + dy * 7 + dx;
        if (((row >> 2) & 3) == kg)
          s_s[wid][dy & 1][cl][dx * 2 + h_] = (_Float16)acc[row >> 4][row & 3];
      }
    const _Float16* srow = &s_s[wid][dy & 1][cl][0];
    #pragma unroll
    for (int dx = 0; dx < 7; ++dx){
      const int pos = (wid + dy) * 22 + (cl + dx);
      f16x2 s2 = *reinterpret_cast<const f16x2*>(srow + dx * 2);
      const int esw = ((pos << 6) + (kg << 4)) ^ ((pos & 7) << 3);
      f16x8 va = *reinterpret_cast<const f16x8*>(&vn_s[esw]);
      f16x8 vb = *reinterpret_cast<const f16x8*>(&vn_s[esw ^ 8]);
      f16x2 p0 = __builtin_shufflevector(va, va, 0, 1);
      f16x2 p1 = __builtin_shufflevector(va, va, 2, 3);
      f16x2 p2 = __builtin_shufflevector(va, va, 4, 5);
      f16x2 p3 = __builtin_shufflevector(va, va, 6, 7);
      f16x2 p4 = __builtin_shufflevector(vb, vb, 0, 1);
      f16x2 p5 = __builtin_shufflevector(vb, vb, 2, 3);
      f16x2 p6 = __builtin_shufflevector(vb, vb, 4, 5);
      f16x2 p7 = __builtin_shufflevector(vb, vb, 6, 7);
      #pragma unroll
      for (int h_ = 0; h_ < 2; ++h_){
        f16x2 sh; sh[0] = s2[h_]; sh[1] = s2[h_];
        accB[h_][0] = sh * p0 + accB[h_][0];
        accB[h_][1] = sh * p1 + accB[h_][1];
        accB[h_][2] = sh * p2 + accB[h_][2];
        accB[h_][3] = sh * p3 + accB[h_][3];
        accB[h_][4] = sh * p4 + accB[h_][4];
        accB[h_][5] = sh * p5 + accB[h_][5];
        accB[h_][6] = sh * p6 + accB[h_][6];
        accB[h_][7] = sh * p7 + accB[h_][7];
      }
    }
  }

  // ---- merge y_c (biased acc, permuted rows) + a_v*band + c_v*ssum ----
  float* ob = out + ((size_t)b * 256) * N_ + pix;
  f32x4 av[4], cv[4];
  #pragma unroll
  for (int vhi = 0; vhi < 4; ++vhi){
    av[vhi] = *reinterpret_cast<const f32x4*>(stats + 128 + kg * 16 + vhi * 4);
    cv[vhi] = *reinterpret_cast<const f32x4*>(stats + 192 + kg * 16 + vhi * 4);
  }
  #pragma unroll
  for (int h_ = 0; h_ < 2; ++h_){
    const float ss = h_ ? ssum1 : ssum0;
    #pragma unroll
    for (int vhi = 0; vhi < 4; ++vhi){
      const int m = 7 + h_ * 4 + vhi;
      #pragma unroll
      for (int r = 0; r < 4; ++r){
        const int j = vhi * 4 + r;                       // v offset in kg chunk
        const int ch = (ha * 2 + h_) * 64 + kg * 16 + j; // output channel
        const float band = (float)accB[h_][j >> 1][j & 1];
        ob[(size_t)ch * N_] = acc[m][r] + av[vhi][r] * band + cv[vhi][r] * ss;
      }
    }
  }
}

extern "C" void kernel_launch(void* const* d_in, const int* in_sizes, int n_in,
                              void* d_out, int out_size, void* d_ws, size_t ws_size,
                              hipStream_t stream){
  (void)in_sizes; (void)n_in; (void)out_size; (void)ws_size;
  const float* x  = (const float*)d_in[0];
  const float* Wq = (const float*)d_in[1];
  const float* Wk = (const float*)d_in[2];
  const float* Wv = (const float*)d_in[3];
  const float* gq = (const float*)d_in[4];
  const float* bq = (const float*)d_in[5];
  const float* gv = (const float*)d_in[6];
  const float* bv = (const float*)d_in[7];
  const float* pw = (const float*)d_in[8];
  const float* pb = (const float*)d_in[9];
  float* out = (float*)d_out;

  char* ws = (char*)d_ws;
  size_t off = 0;
  _Float16* Wcat  = (_Float16*)(ws + off);  off += 131072;                      // 73,728 used
  _Float16* q16   = (_Float16*)(ws + off);  off += (size_t)NT_ * 64 * 2;        // 8,388,608
  _Float16* v16   = (_Float16*)(ws + off);  off += (size_t)NT_ * 64 * 2;        // 8,388,608
  _Float16* ek16  = (_Float16*)(ws + off);  off += (size_t)NT_ * 16 * 2;        // 2,097,152
  _Float16* Wbig2 = (_Float16*)(ws + off);  off += (size_t)B_ * 2 * MH_ * 32 * 2; // 491,520
  float*    Bbig2 = (float*)(ws + off);     off += (size_t)B_ * 2 * MH_ * 4;    // 61,440
  float*    stats = (float*)(ws + off);     off += 1024;
  float*    kstat = (float*)(ws + off);     off += 1024;
  float*    wsumq = (float*)(ws + off);     off += 1024;
  float*    lc_part = (float*)(ws + off);   off += (size_t)1024 * 1024 * 4;     // 4,194,304
  float*    bnpart  = (float*)(ws + off);   off += (size_t)256 * 1024 * 4;      // 1,048,576
  float*    kpart   = (float*)(ws + off);   off += (size_t)256 * 64 * 4;        // 65,536

  k_pack_w <<<144, 256, 0, stream>>>(Wq, Wk, Wv, pw, Wcat, wsumq);
  k_proj   <<<1024, 256, 0, stream>>>(x, Wcat, q16, v16, ek16, bnpart, kpart);
  k_bn2    <<<129, 256, 0, stream>>>(bnpart, kpart, gq, bq, gv, bv, stats, kstat);
  k_lam1   <<<1024, 256, 0, stream>>>(ek16, v16, kstat, lc_part);
  k_makeW  <<<64, 256, 0, stream>>>(stats, lc_part, pw, pb, wsumq, Wbig2, Bbig2);
  dim3 g5(4, 16, 32);
  k_fused  <<<g5, 256, 0, stream>>>(q16, v16, stats, Wbig2, Bbig2, out);
}

// Round 10
// 125.719 us; speedup vs baseline: 3.5904x; 1.3314x over previous
//
#include <hip/hip_runtime.h>

// LambdaLayer2D: B=16, C=256, H=W=64, K=16, HEADS=4, U=1, V=64, R=7
#define B_ 16
#define C_ 256
#define N_ 4096            // H*W
#define NT_ 65536          // B*N
#define MH_ 240            // per-head-pair rows: 98 s + 2 ssum + 12 pad + 128 y_c

typedef _Float16 f16x8 __attribute__((ext_vector_type(8)));
typedef _Float16 f16x4 __attribute__((ext_vector_type(4)));
typedef _Float16 f16x2 __attribute__((ext_vector_type(2)));
typedef float    f32x4 __attribute__((ext_vector_type(4)));

__device__ __forceinline__ float waveSum(float v){
  #pragma unroll
  for (int off = 32; off > 0; off >>= 1) v += __shfl_xor(v, off, 64);
  return v;
}

// ---------------- K0: pack Wq|Wk|Wv -> fp16 [144][256]; wsumq --------
__global__ void k_pack_w(const float* __restrict__ Wq, const float* __restrict__ Wk,
                         const float* __restrict__ Wv, const float* __restrict__ pos_w,
                         _Float16* __restrict__ Wcat, float* __restrict__ wsumq){
  int idx = blockIdx.x * 256 + threadIdx.x;   // 144*256 = 36864
  int row = idx >> 8, col = idx & 255;
  float v;
  if (row < 64)      v = Wq[row * 256 + col];
  else if (row < 80) v = Wk[(row - 64) * 256 + col];
  else               v = Wv[(row - 80) * 256 + col];
  Wcat[idx] = (_Float16)v;
  if (idx < 16){
    float s = 0.f;
    for (int t = 0; t < 49; ++t) s += pos_w[idx * 49 + t];
    wsumq[idx] = s;
  }
}

// ---------------- K1: projection GEMM + BN partials + exp(k) ---------
// Emits: q16/v16 pixel-major f16, ek16[n][16] = exp(k) f16, per-block BN
// partial sums for the 128 BN'd channels, per-block sum-exp partials.
__global__ __launch_bounds__(256) void k_proj(const float* __restrict__ x,
                                              const _Float16* __restrict__ Wcat,
                                              _Float16* __restrict__ q16,
                                              _Float16* __restrict__ v16,
                                              _Float16* __restrict__ ek16,
                                              float* __restrict__ bnpart,
                                              float* __restrict__ kpart){
  __shared__ float bsumW[4][128];
  __shared__ float bssqW[4][128];
  __shared__ float ksumW[4][16];

  const int lane = threadIdx.x & 63;
  const int wid  = threadIdx.x >> 6;
  const int tile = blockIdx.x * 4 + wid;   // 0..4095
  const int j0 = tile << 4;
  const int b  = j0 >> 12;
  const int n0 = j0 & 4095;
  const int cl = lane & 15;
  const int kg = lane >> 4;

  f32x4 acc[9];
  #pragma unroll
  for (int m = 0; m < 9; ++m){ acc[m][0]=0.f; acc[m][1]=0.f; acc[m][2]=0.f; acc[m][3]=0.f; }

  const float* xb = x + (size_t)b * C_ * N_ + n0 + cl;
  #pragma unroll
  for (int kk = 0; kk < 8; ++kk){
    const int kb = kk * 32 + kg * 8;
    f16x8 bfrag;
    #pragma unroll
    for (int jj = 0; jj < 8; ++jj) bfrag[jj] = (_Float16)xb[(size_t)(kb + jj) * N_];
    #pragma unroll
    for (int m = 0; m < 9; ++m){
      f16x8 afrag = *reinterpret_cast<const f16x8*>(Wcat + ((m * 16 + cl) << 8) + kb);
      acc[m] = __builtin_amdgcn_mfma_f32_16x16x32_f16(afrag, bfrag, acc[m], 0, 0, 0);
    }
  }

  // exp(k) rows (Wcat rows 64..79): pixel-major f16 + wave partial sums
  {
    float eks[4];
    f16x4 h4;
    #pragma unroll
    for (int r = 0; r < 4; ++r){ eks[r] = __expf(acc[4][r]); h4[r] = (_Float16)eks[r]; }
    *reinterpret_cast<f16x4*>(ek16 + (((size_t)(j0 + cl)) << 4) + kg * 4) = h4;
    #pragma unroll
    for (int r = 0; r < 4; ++r){
      #pragma unroll
      for (int off = 1; off < 16; off <<= 1) eks[r] += __shfl_xor(eks[r], off, 64);
      if (cl == 0) ksumW[wid][kg * 4 + r] = eks[r];
    }
  }

  // pixel-major f16 q/v
  const size_t prow = ((size_t)(j0 + cl)) << 6;
  #pragma unroll
  for (int m = 0; m < 4; ++m){
    f16x4 h4;
    #pragma unroll
    for (int r = 0; r < 4; ++r) h4[r] = (_Float16)acc[m][r];
    *reinterpret_cast<f16x4*>(q16 + prow + m * 16 + kg * 4) = h4;
  }
  #pragma unroll
  for (int m = 5; m < 9; ++m){
    f16x4 h4;
    #pragma unroll
    for (int r = 0; r < 4; ++r) h4[r] = (_Float16)acc[m][r];
    *reinterpret_cast<f16x4*>(v16 + prow + (m - 5) * 16 + kg * 4) = h4;
  }

  // BN partials: reduce each row over this wave's 16 pixels
  #pragma unroll
  for (int m = 0; m < 9; ++m){
    if (m == 4) continue;
    #pragma unroll
    for (int r = 0; r < 4; ++r){
      float sv = acc[m][r];
      float sq = sv * sv;
      #pragma unroll
      for (int off = 1; off < 16; off <<= 1){
        sv += __shfl_xor(sv, off, 64);
        sq += __shfl_xor(sq, off, 64);
      }
      if (cl == 0){
        int idx = ((m < 4) ? m * 16 : (m - 5) * 16 + 64) + kg * 4 + r;
        bsumW[wid][idx] = sv;
        bssqW[wid][idx] = sq;
      }
    }
  }
  __syncthreads();
  if (threadIdx.x < 128){
    int i = threadIdx.x;
    float s  = bsumW[0][i] + bsumW[1][i] + bsumW[2][i] + bsumW[3][i];
    float sq = bssqW[0][i] + bssqW[1][i] + bssqW[2][i] + bssqW[3][i];
    bnpart[(size_t)i * 1024 + blockIdx.x]         = s;
    bnpart[(size_t)(i + 128) * 1024 + blockIdx.x] = sq;
  } else if (threadIdx.x < 144){
    int t = threadIdx.x - 128;    // kc 0..15
    float s = ksumW[0][t] + ksumW[1][t] + ksumW[2][t] + ksumW[3][t];
    kpart[(size_t)((blockIdx.x >> 6) * 16 + t) * 64 + (blockIdx.x & 63)] = s;
  }
}

// ---------------- K2: finalize BN affine + sum-exp --------------------
// blocks 0..127: BN channel; block 128: kstat[256] = 1/sumexp
// stats layout: [0:64) aq, [64:128) cq, [128:192) av, [192:256) cv
__global__ void k_bn2(const float* __restrict__ bnpart, const float* __restrict__ kpart,
                      const float* __restrict__ gq, const float* __restrict__ bq,
                      const float* __restrict__ gv, const float* __restrict__ bv,
                      float* __restrict__ stats, float* __restrict__ kstat){
  if (blockIdx.x == 128){
    int t = threadIdx.x;          // 0..255 = b*16+kc
    float s = 0.f;
    #pragma unroll
    for (int i = 0; i < 64; ++i) s += kpart[(size_t)t * 64 + i];
    kstat[t] = 1.f / s;
    return;
  }
  const int ch = blockIdx.x;       // 0..127
  const int t = threadIdx.x;
  float s = 0.f, ss = 0.f;
  #pragma unroll
  for (int k = 0; k < 4; ++k){
    int bk = t + k * 256;
    s  += bnpart[(size_t)ch * 1024 + bk];
    ss += bnpart[(size_t)(ch + 128) * 1024 + bk];
  }
  __shared__ float r0[4], r1[4];
  const int lane = t & 63, wid = t >> 6;
  s = waveSum(s); ss = waveSum(ss);
  if (lane == 0){ r0[wid] = s; r1[wid] = ss; }
  __syncthreads();
  if (t == 0){
    s  = r0[0] + r0[1] + r0[2] + r0[3];
    ss = r1[0] + r1[1] + r1[2] + r1[3];
    float mean = s * (1.f / NT_);
    float var  = ss * (1.f / NT_) - mean * mean;   // biased
    float rs = rsqrtf(var + 1e-5f);
    if (ch < 64){
      float a = rs * gq[ch];
      stats[ch] = a; stats[64 + ch] = bq[ch] - mean * a;
    } else {
      int v = ch - 64;
      float a = rs * gv[v];
      stats[128 + v] = a; stats[192 + v] = bv[v] - mean * a;
    }
  }
}

// ---------------- K3: lambda_c partials: 16 kc x 64 v per 64-px slice -
__global__ __launch_bounds__(256) void k_lam1(const _Float16* __restrict__ ek16,
                          const _Float16* __restrict__ v16,
                          const float* __restrict__ kstat,
                          float* __restrict__ lc_part){
  const int blk = blockIdx.x;                 // b*64 + sl
  const int b = blk >> 6, sl = blk & 63;
  const int tid = threadIdx.x;
  const int kc = tid >> 4, vg = tid & 15;
  __shared__ float skb[16][65];

  const size_t base = (size_t)b * N_ + sl * 64;
  if (tid < 128){
    int px = tid >> 1, part = tid & 1;
    f16x8 e8 = *reinterpret_cast<const f16x8*>(ek16 + ((base + px) << 4) + part * 8);
    #pragma unroll
    for (int j = 0; j < 8; ++j)
      skb[part * 8 + j][px] = (float)e8[j] * kstat[b * 16 + part * 8 + j];
  }
  __syncthreads();

  float S0 = 0.f, S1 = 0.f, S2 = 0.f, S3 = 0.f;
  const _Float16* vbase = v16 + (base << 6) + vg * 4;
  #pragma unroll 8
  for (int j = 0; j < 64; ++j){
    f16x4 v4 = *reinterpret_cast<const f16x4*>(vbase + ((size_t)j << 6));
    float sk = skb[kc][j];
    S0 += sk * (float)v4[0];
    S1 += sk * (float)v4[1];
    S2 += sk * (float)v4[2];
    S3 += sk * (float)v4[3];
  }
  float4 w; w.x = S0; w.y = S1; w.z = S2; w.w = S3;
  *reinterpret_cast<float4*>(lc_part + (size_t)blk * 1024 + kc * 64 + vg * 4) = w;
}

// ---------------- K4: build per-(batch, head-pair) weight [240][32] ---
// rows 0..97: s rows (h',tap); 98..99: ssum (h'); 100..111: zero;
// 112..239: y_c rows (h', permuted v). lambda_c finalize folded in.
__global__ void k_makeW(const float* __restrict__ stats, const float* __restrict__ lc_part,
                        const float* __restrict__ pos_w, const float* __restrict__ pos_b,
                        const float* __restrict__ wsumq,
                        _Float16* __restrict__ Wbig2, float* __restrict__ Bbig2){
  const int b = blockIdx.x >> 2, qr = blockIdx.x & 3;
  __shared__ float lcq[16][64];
  for (int o = threadIdx.x; o < 1024; o += 256){
    int kc = o >> 6, v = o & 63;
    float s = 0.f;
    for (int sl = 0; sl < 64; ++sl) s += lc_part[(size_t)(b * 64 + sl) * 1024 + o];
    lcq[kc][v] = stats[128 + v] * s + stats[192 + v] + pos_b[kc];
  }
  __syncthreads();

  const int idx = qr * 120 + threadIdx.x;     // 0..479
  if (threadIdx.x >= 120 || idx >= 480) return;
  const int half = idx / MH_, r = idx % MH_;
  const int rowg = (b * 2 + half) * MH_ + r;
  _Float16* wrow = Wbig2 + ((size_t)rowg << 5);
  float bias = 0.f;
  if (r < 100){
    const int h_ = (r < 98) ? (r / 49) : (r - 98);
    const int h = half * 2 + h_;
    if (r < 98){
      const int tap = r % 49;
      for (int c2 = 0; c2 < 32; ++c2){
        int qc = half * 32 + c2;
        wrow[c2] = (_Float16)(((c2 >> 4) == h_) ? stats[qc] * pos_w[(qc & 15) * 49 + tap] : 0.f);
      }
      for (int k = 0; k < 16; ++k) bias += stats[64 + h * 16 + k] * pos_w[k * 49 + tap];
    } else {
      for (int c2 = 0; c2 < 32; ++c2){
        int qc = half * 32 + c2;
        wrow[c2] = (_Float16)(((c2 >> 4) == h_) ? stats[qc] * wsumq[qc & 15] : 0.f);
      }
      for (int k = 0; k < 16; ++k) bias += stats[64 + h * 16 + k] * wsumq[k];
    }
  } else if (r < 112){
    for (int c2 = 0; c2 < 32; ++c2) wrow[c2] = (_Float16)0.f;
  } else {
    const int t = r - 112, h_ = t >> 6, vv = t & 63;
    const int h = half * 2 + h_;
    // position vv = vhi*16 + kg*4 + r2 holds v = kg*16 + vhi*4 + r2
    const int v = (((vv >> 2) & 3) << 4) | ((vv >> 4) << 2) | (vv & 3);
    for (int c2 = 0; c2 < 32; ++c2){
      int qc = half * 32 + c2;
      wrow[c2] = (_Float16)(((c2 >> 4) == h_) ? stats[qc] * lcq[qc & 15][v] : 0.f);
    }
    for (int k = 0; k < 16; ++k) bias += stats[64 + h * 16 + k] * lcq[k][v];
  }
  Bbig2[rowg] = bias;
}

// ---------------- K5: fused S-GEMM + y_c-GEMM + banded conv ----------
// Head-pair split: grid z = b*2 + half. 16x4 pixel tile, 4 waves. K=32
// MFMA, acc[15]. launch_bounds(256,2) -> 128-reg cap (empirical rule:
// cap = 256/min_waves; 84 spilled, 232 uncapped starved). All 98 S rows
// dumped to per-wave LDS before the band loop so acc[0..6] dies -> band
// live set ~90 regs, fits 128 with no spill. LDS 40,704 B -> 4 blk/CU.
__global__ __launch_bounds__(256, 2) void k_fused(
                        const _Float16* __restrict__ q16,
                        const _Float16* __restrict__ v16,
                        const float* __restrict__ stats,
                        const _Float16* __restrict__ Wbig2,
                        const float* __restrict__ Bbig2,
                        float* __restrict__ out){
  __shared__ _Float16 vn_s[220 * 64];      // 28160 B, XOR-swizzled (16B gran)
  __shared__ _Float16 s_s[4][16][98];      // 12544 B, [wave][pix][tap*2+h']

  const int zb = blockIdx.z;
  const int b = zb >> 1, ha = zb & 1;
  const int x0 = blockIdx.x * 16;
  const int y0 = blockIdx.y * 4;
  const int tid = threadIdx.x;
  const int lane = tid & 63, wid = tid >> 6;
  const int cl = lane & 15, kg = lane >> 4;
  const size_t bN = (size_t)b * N_;

  // ---- vn halo staging: 220 pos x 64 v, coalesced 16B loads ----
  for (int idx = tid; idx < 1760; idx += 256){
    int pos = idx >> 3, c8 = (idx & 7) << 3;
    int yy = pos / 22, xx = pos - yy * 22;
    int gy = y0 + yy - 3, gx = x0 + xx - 3;
    f16x8 val;
    #pragma unroll
    for (int j = 0; j < 8; ++j) val[j] = (_Float16)0.f;
    if ((unsigned)gy < 64u && (unsigned)gx < 64u)
      val = *reinterpret_cast<const f16x8*>(v16 + ((bN + gy * 64 + gx) << 6) + c8);
    int e = (pos << 6) + c8;
    *reinterpret_cast<f16x8*>(&vn_s[e ^ ((pos & 7) << 3)]) = val;
  }

  // ---- MFMA phase: 15 row-tiles, K=32 (this half's q channels) ----
  const int pix = (y0 + wid) * 64 + x0 + cl;
  const _Float16* qp = q16 + ((bN + pix) << 6) + ha * 32;
  f16x8 bfrag = *reinterpret_cast<const f16x8*>(qp + kg * 8);
  const _Float16* Wb = Wbig2 + (((size_t)(b * 2 + ha) * MH_) << 5);
  const float* Bb = Bbig2 + (b * 2 + ha) * MH_;

  f32x4 acc[15];
  #pragma unroll
  for (int m = 0; m < 15; ++m){ acc[m][0]=0.f; acc[m][1]=0.f; acc[m][2]=0.f; acc[m][3]=0.f; }

  #pragma unroll
  for (int m = 0; m < 15; ++m){
    f16x8 a0 = *reinterpret_cast<const f16x8*>(Wb + ((m * 16 + cl) << 5) + kg * 8);
    acc[m] = __builtin_amdgcn_mfma_f32_16x16x32_f16(a0, bfrag, acc[m], 0, 0, 0);
  }

  // ---- bias pre-add (row = m*16 + kg*4 + r for all 15 tiles) ----
  #pragma unroll
  for (int m = 0; m < 15; ++m)
    acc[m] += *reinterpret_cast<const f32x4*>(Bb + m * 16 + kg * 4);

  // ---- ssum rows 98,99 = (m=6, kg=0, r=2/3) -> source lane is cl ----
  const float ssum0 = __shfl(acc[6][2], cl, 64);
  const float ssum1 = __shfl(acc[6][3], cl, 64);

  // ---- dump ALL 98 S rows -> per-wave LDS (frees acc[0..6]) ----
  #pragma unroll
  for (int m = 0; m < 7; ++m){
    #pragma unroll
    for (int r = 0; r < 4; ++r){
      const int row = m * 16 + kg * 4 + r;
      if (row < 98){
        const int pos = (row % 49) * 2 + row / 49;
        s_s[wid][cl][pos] = (_Float16)acc[m][r];
      }
    }
  }
  __syncthreads();   // vn_s ready (s_s is per-wave, covered by lgkmcnt)

  // ---- band: 49 taps; thread owns pixel cl x v in [kg*16,+16) ----
  f16x2 accB[2][8];
  #pragma unroll
  for (int h_ = 0; h_ < 2; ++h_)
    #pragma unroll
    for (int j = 0; j < 8; ++j){ accB[h_][j][0] = (_Float16)0.f; accB[h_][j][1] = (_Float16)0.f; }

  const _Float16* srow = &s_s[wid][cl][0];
  #pragma unroll
  for (int dy = 0; dy < 7; ++dy){
    #pragma unroll
    for (int dx = 0; dx < 7; ++dx){
      const int tap = dy * 7 + dx;
      const int pos = (wid + dy) * 22 + (cl + dx);
      f16x2 s2 = *reinterpret_cast<const f16x2*>(srow + tap * 2);
      const int esw = ((pos << 6) + (kg << 4)) ^ ((pos & 7) << 3);
      f16x8 va = *reinterpret_cast<const f16x8*>(&vn_s[esw]);
      f16x8 vb = *reinterpret_cast<const f16x8*>(&vn_s[esw ^ 8]);
      f16x2 p0 = __builtin_shufflevector(va, va, 0, 1);
      f16x2 p1 = __builtin_shufflevector(va, va, 2, 3);
      f16x2 p2 = __builtin_shufflevector(va, va, 4, 5);
      f16x2 p3 = __builtin_shufflevector(va, va, 6, 7);
      f16x2 p4 = __builtin_shufflevector(vb, vb, 0, 1);
      f16x2 p5 = __builtin_shufflevector(vb, vb, 2, 3);
      f16x2 p6 = __builtin_shufflevector(vb, vb, 4, 5);
      f16x2 p7 = __builtin_shufflevector(vb, vb, 6, 7);
      #pragma unroll
      for (int h_ = 0; h_ < 2; ++h_){
        f16x2 sh; sh[0] = s2[h_]; sh[1] = s2[h_];
        accB[h_][0] = sh * p0 + accB[h_][0];
        accB[h_][1] = sh * p1 + accB[h_][1];
        accB[h_][2] = sh * p2 + accB[h_][2];
        accB[h_][3] = sh * p3 + accB[h_][3];
        accB[h_][4] = sh * p4 + accB[h_][4];
        accB[h_][5] = sh * p5 + accB[h_][5];
        accB[h_][6] = sh * p6 + accB[h_][6];
        accB[h_][7] = sh * p7 + accB[h_][7];
      }
    }
  }

  // ---- merge y_c (biased acc, permuted rows) + a_v*band + c_v*ssum ----
  float* ob = out + ((size_t)b * 256) * N_ + pix;
  f32x4 av[4], cv[4];
  #pragma unroll
  for (int vhi = 0; vhi < 4; ++vhi){
    av[vhi] = *reinterpret_cast<const f32x4*>(stats + 128 + kg * 16 + vhi * 4);
    cv[vhi] = *reinterpret_cast<const f32x4*>(stats + 192 + kg * 16 + vhi * 4);
  }
  #pragma unroll
  for (int h_ = 0; h_ < 2; ++h_){
    const float ss = h_ ? ssum1 : ssum0;
    #pragma unroll
    for (int vhi = 0; vhi < 4; ++vhi){
      const int m = 7 + h_ * 4 + vhi;
      #pragma unroll
      for (int r = 0; r < 4; ++r){
        const int j = vhi * 4 + r;                       // v offset in kg chunk
        const int ch = (ha * 2 + h_) * 64 + kg * 16 + j; // output channel
        const float band = (float)accB[h_][j >> 1][j & 1];
        ob[(size_t)ch * N_] = acc[m][r] + av[vhi][r] * band + cv[vhi][r] * ss;
      }
    }
  }
}

extern "C" void kernel_launch(void* const* d_in, const int* in_sizes, int n_in,
                              void* d_out, int out_size, void* d_ws, size_t ws_size,
                              hipStream_t stream){
  (void)in_sizes; (void)n_in; (void)out_size; (void)ws_size;
  const float* x  = (const float*)d_in[0];
  const float* Wq = (const float*)d_in[1];
  const float* Wk = (const float*)d_in[2];
  const float* Wv = (const float*)d_in[3];
  const float* gq = (const float*)d_in[4];
  const float* bq = (const float*)d_in[5];
  const float* gv = (const float*)d_in[6];
  const float* bv = (const float*)d_in[7];
  const float* pw = (const float*)d_in[8];
  const float* pb = (const float*)d_in[9];
  float* out = (float*)d_out;

  char* ws = (char*)d_ws;
  size_t off = 0;
  _Float16* Wcat  = (_Float16*)(ws + off);  off += 131072;                      // 73,728 used
  _Float16* q16   = (_Float16*)(ws + off);  off += (size_t)NT_ * 64 * 2;        // 8,388,608
  _Float16* v16   = (_Float16*)(ws + off);  off += (size_t)NT_ * 64 * 2;        // 8,388,608
  _Float16* ek16  = (_Float16*)(ws + off);  off += (size_t)NT_ * 16 * 2;        // 2,097,152
  _Float16* Wbig2 = (_Float16*)(ws + off);  off += (size_t)B_ * 2 * MH_ * 32 * 2; // 491,520
  float*    Bbig2 = (float*)(ws + off);     off += (size_t)B_ * 2 * MH_ * 4;    // 61,440
  float*    stats = (float*)(ws + off);     off += 1024;
  float*    kstat = (float*)(ws + off);     off += 1024;
  float*    wsumq = (float*)(ws + off);     off += 1024;
  float*    lc_part = (float*)(ws + off);   off += (size_t)1024 * 1024 * 4;     // 4,194,304
  float*    bnpart  = (float*)(ws + off);   off += (size_t)256 * 1024 * 4;      // 1,048,576
  float*    kpart   = (float*)(ws + off);   off += (size_t)256 * 64 * 4;        // 65,536

  k_pack_w <<<144, 256, 0, stream>>>(Wq, Wk, Wv, pw, Wcat, wsumq);
  k_proj   <<<1024, 256, 0, stream>>>(x, Wcat, q16, v16, ek16, bnpart, kpart);
  k_bn2    <<<129, 256, 0, stream>>>(bnpart, kpart, gq, bq, gv, bv, stats, kstat);
  k_lam1   <<<1024, 256, 0, stream>>>(ek16, v16, kstat, lc_part);
  k_makeW  <<<64, 256, 0, stream>>>(stats, lc_part, pw, pb, wsumq, Wbig2, Bbig2);
  dim3 g5(4, 16, 32);
  k_fused  <<<g5, 256, 0, stream>>>(q16, v16, stats, Wbig2, Bbig2, out);
}